// Round 1
// baseline (111.447 us; speedup 1.0000x reference)
//
#include <hip/hip_runtime.h>

#define NG 512
#define NPX 262144
#define BLOCK 256
#define PXPT 2   // pixels per thread

__global__ __launch_bounds__(BLOCK)
void gsplat_kernel(const float* __restrict__ x,
                   const float* __restrict__ alphas,
                   const float* __restrict__ means,
                   const float* __restrict__ rotations,
                   const float* __restrict__ scales,
                   float* __restrict__ out)
{
    // Per-Gaussian params: (cov00, 2*cov01, cov11, alpha) + (mean_x, mean_y)
    __shared__ float4 gp[NG];
    __shared__ float2 gm[NG];

    // Redundant per-block precompute: 256 threads x 2 Gaussians each.
    for (int n = threadIdx.x; n < NG; n += BLOCK) {
        float rot = rotations[n];
        float sth, cth;
        sincosf(rot, &sth, &cth);
        float s0 = scales[2 * n + 0];
        float s1 = scales[2 * n + 1];
        // RS = [[s0*c, -s1*s], [s0*s, s1*c]]
        float r00 = s0 * cth, r01 = -s1 * sth;
        float r10 = s0 * sth, r11 =  s1 * cth;
        // RSSR = RS * RS^T (symmetric)
        float A = r00 * r00 + r01 * r01;
        float B = r00 * r10 + r01 * r11;
        float D = r10 * r10 + r11 * r11;
        float det = A * D - B * B;
        // cov = inv(RSSR) = [[D, -B], [-B, A]] / det  (same path as reference)
        float c00 =  D / det;
        float c01 = -B / det;
        float c11 =  A / det;
        gp[n] = make_float4(c00, 2.0f * c01, c11, alphas[n]);
        gm[n] = make_float2(means[2 * n + 0], means[2 * n + 1]);
    }
    __syncthreads();

    int tid = blockIdx.x * BLOCK + threadIdx.x;
    // Two pixels per thread: x is (NPX, 2) so one float4 = 2 pixels' coords.
    float4 xv = ((const float4*)x)[tid];
    float x0 = xv.x, y0 = xv.y;
    float x1 = xv.z, y1 = xv.w;

    float acc0 = 0.0f, acc1 = 0.0f;
    #pragma unroll 8
    for (int n = 0; n < NG; ++n) {
        float4 p = gp[n];   // broadcast LDS read
        float2 m = gm[n];
        float dx0 = x0 - m.x, dy0 = y0 - m.y;
        float dx1 = x1 - m.x, dy1 = y1 - m.y;
        // q = c00*dx^2 + 2*c01*dx*dy + c11*dy^2
        float q0 = fmaf(p.x * dx0, dx0, fmaf(p.y * dx0, dy0, p.z * dy0 * dy0));
        float q1 = fmaf(p.x * dx1, dx1, fmaf(p.y * dx1, dy1, p.z * dy1 * dy1));
        acc0 = fmaf(p.w, __expf(-0.5f * q0), acc0);
        acc1 = fmaf(p.w, __expf(-0.5f * q1), acc1);
    }

    ((float2*)out)[tid] = make_float2(acc0, acc1);
}

extern "C" void kernel_launch(void* const* d_in, const int* in_sizes, int n_in,
                              void* d_out, int out_size, void* d_ws, size_t ws_size,
                              hipStream_t stream) {
    const float* x         = (const float*)d_in[0];
    const float* alphas    = (const float*)d_in[1];
    const float* means     = (const float*)d_in[2];
    const float* rotations = (const float*)d_in[3];
    const float* scales    = (const float*)d_in[4];
    float* out = (float*)d_out;

    int grid = NPX / (BLOCK * PXPT);  // 512 blocks
    gsplat_kernel<<<grid, BLOCK, 0, stream>>>(x, alphas, means, rotations, scales, out);
}

// Round 2
// 98.563 us; speedup vs baseline: 1.1307x; 1.1307x over previous
//
#include <hip/hip_runtime.h>

#define NG 512
#define NPX 262144
#define BLOCK 256
#define PXPT 2   // pixels per thread

#if __has_builtin(__builtin_amdgcn_exp2f)
  // native v_exp_f32 (2^x); fold 0.5*log2(e) into the Cholesky factor
  #define KSCALE 0.72134752044448170368f   /* 0.5 * log2(e) */
  #define EXPNEG(w) __builtin_amdgcn_exp2f(-(w))
#else
  // fallback: __expf(x) = v_mul(log2e) + v_exp; fold only the 0.5
  #define KSCALE 0.5f
  #define EXPNEG(w) __expf(-(w))
#endif

__global__ __launch_bounds__(BLOCK, 2)
void gsplat_kernel(const float* __restrict__ x,
                   const float* __restrict__ alphas,
                   const float* __restrict__ means,
                   const float* __restrict__ rotations,
                   const float* __restrict__ scales,
                   float* __restrict__ out)
{
    // Per-Gaussian: (p00, p01, -uoff, alpha) and (p11, -voff)
    // where [p00 p01; 0 p11] is the Cholesky factor of KSCALE*cov and
    // uoff/voff fold the mean:  k*q = (p00*x + p01*y - uoff)^2 + (p11*y - voff)^2
    __shared__ float4 ga[NG];
    __shared__ float2 gb[NG];

    for (int n = threadIdx.x; n < NG; n += BLOCK) {
        float rot = rotations[n];
        float sth, cth;
        sincosf(rot, &sth, &cth);
        float s0 = scales[2 * n + 0];
        float s1 = scales[2 * n + 1];
        // RS = [[s0*c, -s1*s], [s0*s, s1*c]],  RSSR = RS*RS^T
        float r00 = s0 * cth, r01 = -s1 * sth;
        float r10 = s0 * sth, r11 =  s1 * cth;
        float Ar = r00 * r00 + r01 * r01;
        float Br = r00 * r10 + r01 * r11;
        float Dr = r10 * r10 + r11 * r11;
        float det = Ar * Dr - Br * Br;
        // scaled cov: kc = KSCALE * inv(RSSR)
        float kc00 =  KSCALE * Dr / det;
        float kc01 = -KSCALE * Br / det;
        // Cholesky: q*k = (p00*dx + p01*dy)^2 + (p11*dy)^2
        float p00 = sqrtf(kc00);
        float p01 = kc01 / p00;
        float p11 = sqrtf(KSCALE / Dr);   // exact: kc11 - kc01^2/kc00 = KSCALE/Dr
        float mx = means[2 * n + 0];
        float my = means[2 * n + 1];
        float nuoff = -(p00 * mx + p01 * my);
        float nvoff = -(p11 * my);
        ga[n] = make_float4(p00, p01, nuoff, alphas[n]);
        gb[n] = make_float2(p11, nvoff);
    }
    __syncthreads();

    int tid = blockIdx.x * BLOCK + threadIdx.x;
    float4 xv = ((const float4*)x)[tid];   // 2 pixels' (x,y)
    float x0 = xv.x, y0 = xv.y;
    float x1 = xv.z, y1 = xv.w;

    float acc0 = 0.0f, acc1 = 0.0f;
    #pragma unroll 16
    for (int n = 0; n < NG; ++n) {
        float4 a = ga[n];   // broadcast LDS reads
        float2 b = gb[n];
        float u0 = fmaf(a.x, x0, fmaf(a.y, y0, a.z));
        float v0 = fmaf(b.x, y0, b.y);
        float u1 = fmaf(a.x, x1, fmaf(a.y, y1, a.z));
        float v1 = fmaf(b.x, y1, b.y);
        float w0 = fmaf(v0, v0, u0 * u0);
        float w1 = fmaf(v1, v1, u1 * u1);
        acc0 = fmaf(a.w, EXPNEG(w0), acc0);
        acc1 = fmaf(a.w, EXPNEG(w1), acc1);
    }

    ((float2*)out)[tid] = make_float2(acc0, acc1);
}

extern "C" void kernel_launch(void* const* d_in, const int* in_sizes, int n_in,
                              void* d_out, int out_size, void* d_ws, size_t ws_size,
                              hipStream_t stream) {
    const float* x         = (const float*)d_in[0];
    const float* alphas    = (const float*)d_in[1];
    const float* means     = (const float*)d_in[2];
    const float* rotations = (const float*)d_in[3];
    const float* scales    = (const float*)d_in[4];
    float* out = (float*)d_out;

    int grid = NPX / (BLOCK * PXPT);  // 512 blocks
    gsplat_kernel<<<grid, BLOCK, 0, stream>>>(x, alphas, means, rotations, scales, out);
}

// Round 3
// 91.841 us; speedup vs baseline: 1.2135x; 1.0732x over previous
//
#include <hip/hip_runtime.h>

#define NG 512
#define NPX 262144
#define BLOCK 256
#define GTILE 8   // Gaussians per register tile

#if __has_builtin(__builtin_amdgcn_exp2f)
  #define KSCALE 0.72134752044448170368f   /* 0.5 * log2(e) */
  #define EXPNEG(w) __builtin_amdgcn_exp2f(-(w))
#else
  #define KSCALE 0.5f
  #define EXPNEG(w) __expf(-(w))
#endif

__global__ __launch_bounds__(BLOCK, 4)
void gsplat_kernel(const float* __restrict__ x,
                   const float* __restrict__ alphas,
                   const float* __restrict__ means,
                   const float* __restrict__ rotations,
                   const float* __restrict__ scales,
                   float* __restrict__ out)
{
    // Per-Gaussian: (p00, p01, -uoff, alpha) and (p11, -voff)
    // k*q = (p00*x + p01*y - uoff)^2 + (p11*y - voff)^2, k = 0.5*log2(e)
    __shared__ float4 ga[NG];
    __shared__ float2 gb[NG];

    for (int n = threadIdx.x; n < NG; n += BLOCK) {
        float rot = rotations[n];
        float sth, cth;
        sincosf(rot, &sth, &cth);
        float s0 = scales[2 * n + 0];
        float s1 = scales[2 * n + 1];
        float r00 = s0 * cth, r01 = -s1 * sth;
        float r10 = s0 * sth, r11 =  s1 * cth;
        float Ar = r00 * r00 + r01 * r01;
        float Br = r00 * r10 + r01 * r11;
        float Dr = r10 * r10 + r11 * r11;
        float det = Ar * Dr - Br * Br;
        float kc00 =  KSCALE * Dr / det;
        float kc01 = -KSCALE * Br / det;
        float p00 = sqrtf(kc00);
        float p01 = kc01 / p00;
        float p11 = sqrtf(KSCALE / Dr);
        float mx = means[2 * n + 0];
        float my = means[2 * n + 1];
        float nuoff = -(p00 * mx + p01 * my);
        float nvoff = -(p11 * my);
        ga[n] = make_float4(p00, p01, nuoff, alphas[n]);
        gb[n] = make_float2(p11, nvoff);
    }
    __syncthreads();

    int tid = blockIdx.x * BLOCK + threadIdx.x;
    float2 xv = ((const float2*)x)[tid];   // one pixel per thread
    float x0 = xv.x, y0 = xv.y;

    float acc0 = 0.0f, acc1 = 0.0f;
    for (int t = 0; t < NG; t += GTILE) {
        // batched LDS reads into registers: one lgkmcnt wait per tile
        float4 a[GTILE];
        float2 b[GTILE];
        #pragma unroll
        for (int j = 0; j < GTILE; ++j) {
            a[j] = ga[t + j];
            b[j] = gb[t + j];
        }
        #pragma unroll
        for (int j = 0; j < GTILE; ++j) {
            float u = fmaf(a[j].x, x0, fmaf(a[j].y, y0, a[j].z));
            float v = fmaf(b[j].x, y0, b[j].y);
            float w = fmaf(v, v, u * u);
            float e = EXPNEG(w);
            if (j & 1) acc1 = fmaf(a[j].w, e, acc1);
            else       acc0 = fmaf(a[j].w, e, acc0);
        }
    }

    out[tid] = acc0 + acc1;
}

extern "C" void kernel_launch(void* const* d_in, const int* in_sizes, int n_in,
                              void* d_out, int out_size, void* d_ws, size_t ws_size,
                              hipStream_t stream) {
    const float* x         = (const float*)d_in[0];
    const float* alphas    = (const float*)d_in[1];
    const float* means     = (const float*)d_in[2];
    const float* rotations = (const float*)d_in[3];
    const float* scales    = (const float*)d_in[4];
    float* out = (float*)d_out;

    int grid = NPX / BLOCK;  // 1024 blocks -> 4 blocks/CU, 16 waves/CU
    gsplat_kernel<<<grid, BLOCK, 0, stream>>>(x, alphas, means, rotations, scales, out);
}